// Round 4
// baseline (247.626 us; speedup 1.0000x reference)
//
#include <hip/hip_runtime.h>
#include <hip/hip_bf16.h>
#include <hip/hip_fp16.h>

#define SEQ 2048
#define DH  64
#define NH  16
#define DE  1024   // NH*DH

typedef float    f32x4  __attribute__((ext_vector_type(4)));
typedef float    fvec4  __attribute__((ext_vector_type(4)));
typedef __bf16   bf16x8 __attribute__((ext_vector_type(8)));
typedef _Float16 f16x4  __attribute__((ext_vector_type(4)));

#define MFMA_BF16_K32(A,B,C) __builtin_amdgcn_mfma_f32_16x16x32_bf16(A,B,C,0,0,0)
#define MFMA_F16_K16(A,B,C)  __builtin_amdgcn_mfma_f32_16x16x16f16(A,B,C,0,0,0)

// async 16B global -> LDS (wave-uniform base + lane*16)
__device__ __forceinline__ void gll16(void* lds, const void* g) {
    __builtin_amdgcn_global_load_lds(
        (const __attribute__((address_space(1))) unsigned int*)g,
        (__attribute__((address_space(3))) unsigned int*)lds, 16, 0, 0);
}

// ---------------------------------------------------------------------------
// One-shot f32 -> bf16 prep: xb, wqb, wkb(*0.125), wvb, wotb(transposed WO).
// ---------------------------------------------------------------------------
__global__ __launch_bounds__(256) void conv_all(
    const float* __restrict__ x,  const float* __restrict__ Wq,
    const float* __restrict__ Wk, const float* __restrict__ Wv,
    const float* __restrict__ Wo, __bf16* __restrict__ xb,
    __bf16* __restrict__ wqb, __bf16* __restrict__ wkb,
    __bf16* __restrict__ wvb, __bf16* __restrict__ wotb)
{
    long i = ((long)blockIdx.x * 256 + threadIdx.x) * 8;
    const float* src; __bf16* dst; float sc = 1.0f; long j;
    if (i < 2097152)      { j = i;            src = x  + j; dst = xb  + j; }
    else if (i < 3145728) { j = i - 2097152;  src = Wq + j; dst = wqb + j; }
    else if (i < 4194304) { j = i - 3145728;  src = Wk + j; dst = wkb + j; sc = 0.125f; }
    else if (i < 5242880) { j = i - 4194304;  src = Wv + j; dst = wvb + j; }
    else                  { j = i - 5242880;  src = Wo + j;
                            long a = j >> 16, e = (j >> 6) & 1023, h = j & 63;
                            dst = wotb + e * DE + a * 64 + h; }
    fvec4 u = *(const fvec4*)src;
    fvec4 w = *(const fvec4*)(src + 4);
    bf16x8 o;
    o[0]=(__bf16)(u.x*sc); o[1]=(__bf16)(u.y*sc); o[2]=(__bf16)(u.z*sc); o[3]=(__bf16)(u.w*sc);
    o[4]=(__bf16)(w.x*sc); o[5]=(__bf16)(w.y*sc); o[6]=(__bf16)(w.z*sc); o[7]=(__bf16)(w.w*sc);
    *(bf16x8*)dst = o;
}

// ---------------------------------------------------------------------------
// m97-density GEMM: C[m,n] = sum_k A[m,k]*B[n,k], bf16 in, BM=128 BN=64 BK=64,
// 256 thr = 4 waves, wave-tile 64x32 (4m x 2n), 16 MFMA/wave/barrier,
// global_load_lds(16B) staging (6/thread/iter), 24 KB LDS.
// MODE 0: fused QKV (N=3072): segment zi=bn>>10 -> q/k as [a][c][h] bf16,
//         v as [a][h][c] f16 (transposed).  MODE 1: f32 row-major out.
// ---------------------------------------------------------------------------
template<int MODE>
__global__ __launch_bounds__(256) void gemm128(
    const __bf16* __restrict__ A, const __bf16* __restrict__ B,
    __bf16* __restrict__ Cqk, __half* __restrict__ Cv, float* __restrict__ Cf)
{
    __shared__ __bf16 As[128][64];   // 16 KB
    __shared__ __bf16 Bs[64][64];    // 8 KB

    const int t = threadIdx.x, wave = t >> 6, lane = t & 63;
    const int bm = blockIdx.y * 128, bn = blockIdx.x * 64;
    const int il = lane & 15, q4 = lane >> 4;
    const int wm = (wave & 1) * 64, wn = (wave >> 1) * 32;

    // staging maps: segment s -> row s>>3, 16B chunk (s&7)
    int sA[4], sB[2];
    #pragma unroll
    for (int i = 0; i < 4; ++i) sA[i] = i * 256 + t;
    #pragma unroll
    for (int i = 0; i < 2; ++i) sB[i] = i * 256 + t;

    f32x4 acc[4][2];
    #pragma unroll
    for (int i = 0; i < 4; ++i)
        #pragma unroll
        for (int j = 0; j < 2; ++j) acc[i][j] = (f32x4){0.f,0.f,0.f,0.f};

    for (int k0 = 0; k0 < DE; k0 += 64) {
        __syncthreads();
        #pragma unroll
        for (int i = 0; i < 4; ++i)
            gll16((__bf16*)As + sA[i]*8,
                  A + (long)(bm + (sA[i] >> 3)) * DE + k0 + (sA[i] & 7) * 8);
        #pragma unroll
        for (int i = 0; i < 2; ++i)
            gll16((__bf16*)Bs + sB[i]*8,
                  B + (long)(bn + (sB[i] >> 3)) * DE + k0 + (sB[i] & 7) * 8);
        __syncthreads();
        #pragma unroll
        for (int kc = 0; kc < 2; ++kc) {
            bf16x8 af[4], bff[2];
            #pragma unroll
            for (int mt = 0; mt < 4; ++mt)
                af[mt] = *(const bf16x8*)&As[wm + mt*16 + il][kc*32 + q4*8];
            #pragma unroll
            for (int nt = 0; nt < 2; ++nt)
                bff[nt] = *(const bf16x8*)&Bs[wn + nt*16 + il][kc*32 + q4*8];
            #pragma unroll
            for (int mt = 0; mt < 4; ++mt)
                #pragma unroll
                for (int nt = 0; nt < 2; ++nt)
                    acc[mt][nt] = MFMA_BF16_K32(af[mt], bff[nt], acc[mt][nt]);
        }
    }

    if (MODE == 0) {
        const int zi   = bn >> 10;          // 0=q 1=k 2=v (uniform per block)
        const int head = (bn >> 6) & 15;
        #pragma unroll
        for (int mt = 0; mt < 4; ++mt) {
            const int m0 = bm + wm + mt*16 + q4*4;
            #pragma unroll
            for (int nt = 0; nt < 2; ++nt) {
                const int h = wn + nt*16 + il;           // 0..63
                #pragma unroll
                for (int r = 0; r < 4; ++r) {
                    if (zi == 2)
                        Cv[(long)head*131072 + (long)h*2048 + (m0 + r)] =
                            (__half)acc[mt][nt][r];
                    else
                        Cqk[(long)zi*2097152 + (long)head*131072 +
                            (long)(m0 + r)*64 + h] = (__bf16)acc[mt][nt][r];
                }
            }
        }
    } else {
        #pragma unroll
        for (int mt = 0; mt < 4; ++mt) {
            const int m0 = bm + wm + mt*16 + q4*4;
            #pragma unroll
            for (int nt = 0; nt < 2; ++nt) {
                const int n = bn + wn + nt*16 + il;
                #pragma unroll
                for (int r = 0; r < 4; ++r)
                    Cf[(long)(m0 + r) * DE + n] = acc[mt][nt][r];
            }
        }
    }
}

// ---------------------------------------------------------------------------
// Transposed-S MFMA flash attention, NO LDS in the K-loop.
// Reference roles: s[c,C] = k_c·q_C/8 (K pre-scaled), causal C<=c.
// Grid (NH, 32): jt = 31-by. 8 waves: wsub=wave&3 -> 16-row c-strip,
// half=wave>>2 -> half of the C-range (split-C, combine by addition: no
// max-subtraction needed since |s| <= ~8).
// Trick: T = MFMA(A=Q-frag, B=K-frag) gives T[m=C][n=c]; per-lane that is
// (c=lane&15, C=(lane>>4)*4+r) == A-fragment layout of mfma_f32_16x16x16f16.
// So exp(T) packs straight into the PV A-operand — no transpose anywhere.
// Rowsum l via MFMA with ones-B (C/D layout == O layout -> elementwise div).
// ---------------------------------------------------------------------------
__global__ __launch_bounds__(512, 4) void attn_mfma(
    const __bf16* __restrict__ Qb, const __bf16* __restrict__ Kb,
    const __half* __restrict__ Vt, __bf16* __restrict__ Z)
{
    __shared__ struct { float O[4][64][20]; float l[4][64][4]; } sm; // 24 KB

    const int a    = blockIdx.x;
    const int jt   = 31 - (int)blockIdx.y;
    const int t    = threadIdx.x;
    const int wave = t >> 6;
    const int lane = t & 63;
    const int half = wave >> 2;
    const int wsub = wave & 3;
    const int c0   = jt * 64;
    const int il   = lane & 15;
    const int q4   = lane >> 4;

    const int h0   = (jt + 2) >> 1;                  // tiles in half 0
    const int nbeg = half ? h0 * 64 : 0;
    const int nend = half ? c0 : (h0 - 1) * 64;      // inclusive
    const bool owns_diag = (jt == 0) ? (half == 0) : (half == 1);

    // K B-fragments: fixed c-rows for this wave
    const __bf16* kp = Kb + ((long)a*SEQ + c0 + wsub*16 + il)*DH + q4*8;
    bf16x8 kf0 = *(const bf16x8*)(kp);
    bf16x8 kf1 = *(const bf16x8*)(kp + 32);

    f16x4 ones;
    #pragma unroll
    for (int j = 0; j < 4; ++j) ones[j] = (_Float16)1.0f;

    f32x4 o[4];
    #pragma unroll
    for (int ht = 0; ht < 4; ++ht) o[ht] = (f32x4){0.f,0.f,0.f,0.f};
    f32x4 lacc = {0.f,0.f,0.f,0.f};

    const __bf16* qh = Qb + (long)a * SEQ * DH;
    const __half* vh = Vt + (long)a * DH * SEQ;

    // ---- full (unmasked) tiles
    const int fend = (nend < c0 - 64) ? nend : (c0 - 64);
    for (int n0 = nbeg; n0 <= fend; n0 += 64) {
        #pragma unroll
        for (int cc = 0; cc < 4; ++cc) {
            const int Cb = n0 + cc * 16;
            const __bf16* qp = qh + (long)(Cb + il)*DH + q4*8;
            bf16x8 qf0 = *(const bf16x8*)(qp);
            bf16x8 qf1 = *(const bf16x8*)(qp + 32);
            f32x4 T = {0.f,0.f,0.f,0.f};
            T = MFMA_BF16_K32(qf0, kf0, T);
            T = MFMA_BF16_K32(qf1, kf1, T);
            f16x4 pf;
            #pragma unroll
            for (int r = 0; r < 4; ++r) pf[r] = (_Float16)__expf(T[r]);
            lacc = MFMA_F16_K16(pf, ones, lacc);
            #pragma unroll
            for (int ht = 0; ht < 4; ++ht) {
                f16x4 vf = *(const f16x4*)(vh + (long)(ht*16 + il)*SEQ + Cb + q4*4);
                o[ht] = MFMA_F16_K16(pf, vf, o[ht]);
            }
        }
    }

    // ---- diagonal tile (chunks cc>wsub fully masked -> skipped)
    if (owns_diag) {
        const int n0 = c0;
        for (int cc = 0; cc <= wsub; ++cc) {
            const int Cb = n0 + cc * 16;
            const __bf16* qp = qh + (long)(Cb + il)*DH + q4*8;
            bf16x8 qf0 = *(const bf16x8*)(qp);
            bf16x8 qf1 = *(const bf16x8*)(qp + 32);
            f32x4 T = {0.f,0.f,0.f,0.f};
            T = MFMA_BF16_K32(qf0, kf0, T);
            T = MFMA_BF16_K32(qf1, kf1, T);
            if (cc == wsub) {   // partial mask: C > c  (C=cc*16+q4*4+r, c=wsub*16+il)
                #pragma unroll
                for (int r = 0; r < 4; ++r)
                    if (cc*16 + q4*4 + r > wsub*16 + il) T[r] = -1e30f;
            }
            f16x4 pf;
            #pragma unroll
            for (int r = 0; r < 4; ++r) pf[r] = (_Float16)__expf(T[r]);
            lacc = MFMA_F16_K16(pf, ones, lacc);
            #pragma unroll
            for (int ht = 0; ht < 4; ++ht) {
                f16x4 vf = *(const f16x4*)(vh + (long)(ht*16 + il)*SEQ + Cb + q4*4);
                o[ht] = MFMA_F16_K16(pf, vf, o[ht]);
            }
        }
    }

    // ---- combine halves via LDS (padded stride 20 -> all 32 banks covered)
    __syncthreads();
    if (half) {
        #pragma unroll
        for (int ht = 0; ht < 4; ++ht)
            *(f32x4*)&sm.O[wsub][lane][ht*4] = o[ht];
        *(f32x4*)&sm.l[wsub][lane][0] = lacc;
    }
    __syncthreads();
    if (!half) {
        #pragma unroll
        for (int ht = 0; ht < 4; ++ht)
            o[ht] += *(const f32x4*)&sm.O[wsub][lane][ht*4];
        lacc += *(const f32x4*)&sm.l[wsub][lane][0];
        float inv[4];
        #pragma unroll
        for (int r = 0; r < 4; ++r) inv[r] = 1.0f / lacc[r];
        // O C/D layout: row (=c-local) = q4*4+r, col (=h-local) = ht*16+il
        #pragma unroll
        for (int ht = 0; ht < 4; ++ht)
            #pragma unroll
            for (int r = 0; r < 4; ++r) {
                long row = c0 + wsub*16 + q4*4 + r;
                Z[row * DE + a*64 + ht*16 + il] = (__bf16)(o[ht][r] * inv[r]);
            }
    }
}

// ---------------------------------------------------------------------------
extern "C" void kernel_launch(void* const* d_in, const int* in_sizes, int n_in,
                              void* d_out, int out_size, void* d_ws, size_t ws_size,
                              hipStream_t stream)
{
    const float* x  = (const float*)d_in[0];
    const float* Wq = (const float*)d_in[1];
    const float* Wk = (const float*)d_in[2];
    const float* Wv = (const float*)d_in[3];
    const float* Wo = (const float*)d_in[4];
    float* out = (float*)d_out;

    const long M1 = 1024 * 1024;
    __bf16* wsb  = (__bf16*)d_ws;              // 14M 2B elems = 28 MB
    __bf16* xb   = wsb;                        // [c][e]        2M
    __bf16* wqb  = wsb + 2*M1;                 // [a*64+h][e]   1M  (B rows 0..1023)
    // wkb = wsb+3*M1 (pre-scaled .125), wvb = wsb+4*M1 — contiguous with wqb
    __bf16* wkb  = wsb + 3*M1;
    __bf16* wvb  = wsb + 4*M1;
    __bf16* wotb = wsb + 5*M1;                 // [e][a*64+h]   1M
    __bf16* qb   = wsb + 6*M1;                 // [a][c][h] bf16 2M
    __bf16* kb   = wsb + 8*M1;                 // (not addressed directly below)
    __half* vtb  = (__half*)(wsb + 10*M1);     // [a][h][c] f16  2M
    __bf16* zb   = wsb + 12*M1;                // [c][a*64+h]   2M
    (void)wkb; (void)wvb; (void)kb;

    conv_all<<<3072, 256, 0, stream>>>(x, Wq, Wk, Wv, Wo,
                                       xb, wqb, wsb + 3*M1, wsb + 4*M1, wotb);

    // fused QKV: B = [wq|wk|wv] (3072 x 1024), store q/k bf16 + v^T f16
    gemm128<0><<<dim3(48, 16), 256, 0, stream>>>(xb, wqb, qb, vtb, nullptr);

    attn_mfma<<<dim3(NH, 32), 512, 0, stream>>>(qb, wsb + 6*M1 + 2*M1, vtb, zb);

    // output projection: out = Z · WoT^T (f32 out)
    gemm128<1><<<dim3(16, 16), 256, 0, stream>>>(zb, wotb, nullptr, nullptr, out);
}

// Round 5
// 206.882 us; speedup vs baseline: 1.1969x; 1.1969x over previous
//
#include <hip/hip_runtime.h>
#include <hip/hip_bf16.h>
#include <hip/hip_fp16.h>

#define SEQ 2048
#define DH  64
#define NH  16
#define DE  1024   // NH*DH

typedef float    f32x4  __attribute__((ext_vector_type(4)));
typedef float    fvec4  __attribute__((ext_vector_type(4)));
typedef __bf16   bf16x8 __attribute__((ext_vector_type(8)));
typedef _Float16 half8  __attribute__((ext_vector_type(8)));
typedef _Float16 f16x4  __attribute__((ext_vector_type(4)));

#define MFMA_BF16_K32(A,B,C) __builtin_amdgcn_mfma_f32_16x16x32_bf16(A,B,C,0,0,0)
#define MFMA_F16_K32(A,B,C)  __builtin_amdgcn_mfma_f32_16x16x32_f16(A,B,C,0,0,0)
#define MFMA_F16_K16(A,B,C)  __builtin_amdgcn_mfma_f32_16x16x16f16(A,B,C,0,0,0)

// async 16B global -> LDS (dst forced to wave-uniform base + lane*16)
__device__ __forceinline__ void gll16(void* lds, const void* g) {
    __builtin_amdgcn_global_load_lds(
        (const __attribute__((address_space(1))) unsigned int*)g,
        (__attribute__((address_space(3))) unsigned int*)lds, 16, 0, 0);
}

// ---------------------------------------------------------------------------
// One-shot f32 -> bf16 prep: xb, wqb, wkb(*0.125), wvb, wotb(transposed WO).
// ---------------------------------------------------------------------------
__global__ __launch_bounds__(256) void conv_all(
    const float* __restrict__ x,  const float* __restrict__ Wq,
    const float* __restrict__ Wk, const float* __restrict__ Wv,
    const float* __restrict__ Wo, __bf16* __restrict__ xb,
    __bf16* __restrict__ wqb, __bf16* __restrict__ wkb,
    __bf16* __restrict__ wvb, __bf16* __restrict__ wotb)
{
    long i = ((long)blockIdx.x * 256 + threadIdx.x) * 8;
    const float* src; __bf16* dst; float sc = 1.0f; long j;
    if (i < 2097152)      { j = i;            src = x  + j; dst = xb  + j; }
    else if (i < 3145728) { j = i - 2097152;  src = Wq + j; dst = wqb + j; }
    else if (i < 4194304) { j = i - 3145728;  src = Wk + j; dst = wkb + j; sc = 0.125f; }
    else if (i < 5242880) { j = i - 4194304;  src = Wv + j; dst = wvb + j; }
    else                  { j = i - 5242880;  src = Wo + j;
                            long a = j >> 16, e = (j >> 6) & 1023, h = j & 63;
                            dst = wotb + e * DE + a * 64 + h; }
    fvec4 u = *(const fvec4*)src;
    fvec4 w = *(const fvec4*)(src + 4);
    bf16x8 o;
    o[0]=(__bf16)(u.x*sc); o[1]=(__bf16)(u.y*sc); o[2]=(__bf16)(u.z*sc); o[3]=(__bf16)(u.w*sc);
    o[4]=(__bf16)(w.x*sc); o[5]=(__bf16)(w.y*sc); o[6]=(__bf16)(w.z*sc); o[7]=(__bf16)(w.w*sc);
    *(bf16x8*)dst = o;
}

// ---------------------------------------------------------------------------
// GEMM: C[m,n] = sum_k A[m,k]*B[n,k], bf16 in, BM=128 BN=64 BK=64,
// 256 thr = 4 waves, wave-tile 64x32. global_load_lds(16B) staging with
// SOURCE-SIDE XOR SWIZZLE: LDS slot (row, c) holds global chunk c^(row&7).
// gll16 can't scatter LDS writes (dst = uniform+lane*16), so we permute the
// GLOBAL chunk each lane fetches instead; readers XOR identically. This
// spreads fragment reads (16 rows x same column) over all 32 banks:
// was a 16-way conflict (~5.7x, the R3/R4 GEMM killer), now ~free.
// MODE 0: fused QKV (N=3072): zi=bn>>10 -> q/k [a][c][h] f16, v^T [a][h][c] f16.
// MODE 1: f32 row-major out (output projection).
// ---------------------------------------------------------------------------
template<int MODE>
__global__ __launch_bounds__(256) void gemm128(
    const __bf16* __restrict__ A, const __bf16* __restrict__ B,
    __half* __restrict__ Cqk, __half* __restrict__ Cv, float* __restrict__ Cf)
{
    __shared__ __bf16 As[128][64];   // 16 KB (swizzled chunk order)
    __shared__ __bf16 Bs[64][64];    // 8 KB

    const int t = threadIdx.x, wave = t >> 6, lane = t & 63;
    const int bm = blockIdx.y * 128, bn = blockIdx.x * 64;
    const int il = lane & 15, q4 = lane >> 4;
    const int wm = (wave & 1) * 64, wn = (wave >> 1) * 32;

    f32x4 acc[4][2];
    #pragma unroll
    for (int i = 0; i < 4; ++i)
        #pragma unroll
        for (int j = 0; j < 2; ++j) acc[i][j] = (f32x4){0.f,0.f,0.f,0.f};

    for (int k0 = 0; k0 < DE; k0 += 64) {
        __syncthreads();
        #pragma unroll
        for (int i = 0; i < 4; ++i) {
            int s = i * 256 + t, row = s >> 3, ch = (s & 7) ^ (row & 7);
            gll16((__bf16*)As + (long)s * 8,
                  A + (long)(bm + row) * DE + k0 + ch * 8);
        }
        #pragma unroll
        for (int i = 0; i < 2; ++i) {
            int s = i * 256 + t, row = s >> 3, ch = (s & 7) ^ (row & 7);
            gll16((__bf16*)Bs + (long)s * 8,
                  B + (long)(bn + row) * DE + k0 + ch * 8);
        }
        __syncthreads();
        #pragma unroll
        for (int kc = 0; kc < 2; ++kc) {
            bf16x8 af[4], bff[2];
            #pragma unroll
            for (int mt = 0; mt < 4; ++mt) {
                int row = wm + mt*16 + il, ch = (kc*4 + q4) ^ (row & 7);
                af[mt] = *(const bf16x8*)&As[row][ch * 8];
            }
            #pragma unroll
            for (int nt = 0; nt < 2; ++nt) {
                int row = wn + nt*16 + il, ch = (kc*4 + q4) ^ (row & 7);
                bff[nt] = *(const bf16x8*)&Bs[row][ch * 8];
            }
            #pragma unroll
            for (int mt = 0; mt < 4; ++mt)
                #pragma unroll
                for (int nt = 0; nt < 2; ++nt)
                    acc[mt][nt] = MFMA_BF16_K32(af[mt], bff[nt], acc[mt][nt]);
        }
    }

    if (MODE == 0) {
        const int zi   = bn >> 10;          // 0=q 1=k 2=v (uniform per block)
        const int head = (bn >> 6) & 15;
        #pragma unroll
        for (int mt = 0; mt < 4; ++mt) {
            const int m0 = bm + wm + mt*16 + q4*4;
            #pragma unroll
            for (int nt = 0; nt < 2; ++nt) {
                const int h = wn + nt*16 + il;           // 0..63
                #pragma unroll
                for (int r = 0; r < 4; ++r) {
                    if (zi == 2)
                        Cv[(long)head*131072 + (long)h*2048 + (m0 + r)] =
                            (__half)acc[mt][nt][r];
                    else
                        Cqk[(long)zi*2097152 + (long)head*131072 +
                            (long)(m0 + r)*64 + h] = (__half)acc[mt][nt][r];
                }
            }
        }
    } else {
        #pragma unroll
        for (int mt = 0; mt < 4; ++mt) {
            const int m0 = bm + wm + mt*16 + q4*4;
            #pragma unroll
            for (int nt = 0; nt < 2; ++nt) {
                const int n = bn + wn + nt*16 + il;
                #pragma unroll
                for (int r = 0; r < 4; ++r)
                    Cf[(long)(m0 + r) * DE + n] = acc[mt][nt][r];
            }
        }
    }
}

// ---------------------------------------------------------------------------
// Out-projection input is bf16; reuse gemm128 by converting Z in the attn
// epilogue to bf16? No — attn writes f16 now... Keep A-operand generic:
// a tiny bf16 view is avoided by storing Z as bf16 from attn (see below).
// (gemm128 A/B are bf16; attn writes zb as bf16.)
// ---------------------------------------------------------------------------

// ---------------------------------------------------------------------------
// Transposed-S MFMA flash attention, register-only K-loop with explicit
// chunk-level prefetch.  Reference roles: s[c,C]=k_c·q_C/8 (K pre-scaled),
// causal C<=c.  Grid (NH, 32), jt = 31-by (big first), 1024 thr = 16 waves:
//   wsub = wave&3  -> 16-row c-strip (rows c0+wsub*16..+16)
//   qtr  = wave>>2 -> quarter of this strip's C-chunks (16-col granularity)
// Strip has M = jt*4+wsub+1 chunks; chunk M-1 is the diagonal (masked).
// Split-C partials combine by plain addition (no max-subtraction softmax:
// |s| <= ~8 sigma, exp safe in f32).
// Per chunk: T=MFMA(Q-frag, K-frag) gives Sᵀ whose per-lane C/D layout ==
// the A-fragment layout of mfma 16x16x16 f16 -> exp(T) feeds PV directly,
// no LDS/transpose. Rowsum via ones-B MFMA (C/D layout == O layout).
// Next chunk's Q+V are loaded before computing the current chunk.
// ---------------------------------------------------------------------------
__global__ __launch_bounds__(1024, 4) void attn_mfma(
    const __half* __restrict__ Qh, const __half* __restrict__ Kh,
    const __half* __restrict__ Vt, __bf16* __restrict__ Z)
{
    __shared__ float smc[3][4][64][20];   // 61440 B combine buffer

    const int a    = blockIdx.x;
    const int jt   = 31 - (int)blockIdx.y;
    const int t    = threadIdx.x;
    const int wave = t >> 6;
    const int lane = t & 63;
    const int qtr  = wave >> 2;
    const int wsub = wave & 3;
    const int c0   = jt * 64;
    const int il   = lane & 15;
    const int q4   = lane >> 4;

    const int M    = jt*4 + wsub + 1;          // chunks for this strip
    const int mbeg = (qtr * M) >> 2;
    const int mend = ((qtr + 1) * M) >> 2;     // quarter 3 owns diag (M-1)

    const __half* qh = Qh + (long)a * SEQ * DH;
    const __half* vh = Vt + (long)a * DH * SEQ;

    // K B-fragments: fixed c-rows for this strip
    const __half* kp = Kh + ((long)a*SEQ + c0 + wsub*16 + il)*DH + q4*8;
    half8 kf0 = *(const half8*)(kp);
    half8 kf1 = *(const half8*)(kp + 32);

    f16x4 ones;
    #pragma unroll
    for (int j = 0; j < 4; ++j) ones[j] = (_Float16)1.0f;

    f32x4 o[4];
    #pragma unroll
    for (int ht = 0; ht < 4; ++ht) o[ht] = (f32x4){0.f,0.f,0.f,0.f};
    f32x4 lacc = {0.f,0.f,0.f,0.f};

    if (mbeg < mend) {
        const __half* qp = qh + (long)(mbeg*16 + il)*DH + q4*8;
        half8 qa = *(const half8*)(qp);
        half8 qb = *(const half8*)(qp + 32);
        f16x4 va[4];
        #pragma unroll
        for (int ht = 0; ht < 4; ++ht)
            va[ht] = *(const f16x4*)(vh + (long)(ht*16 + il)*SEQ + mbeg*16 + q4*4);

        for (int m = mbeg; m < mend; ++m) {
            // ---- prefetch chunk m+1 (clamped; loads issue before any use)
            const int mn = (m + 1 < mend) ? m + 1 : m;
            const __half* qpn = qh + (long)(mn*16 + il)*DH + q4*8;
            half8 qa_n = *(const half8*)(qpn);
            half8 qb_n = *(const half8*)(qpn + 32);
            f16x4 va_n[4];
            #pragma unroll
            for (int ht = 0; ht < 4; ++ht)
                va_n[ht] = *(const f16x4*)(vh + (long)(ht*16 + il)*SEQ + mn*16 + q4*4);

            // ---- T = Sᵀ chunk: lane (il,q4) reg r = P-input[c=il][C=q4*4+r]
            f32x4 T = {0.f,0.f,0.f,0.f};
            T = MFMA_F16_K32(qa, kf0, T);
            T = MFMA_F16_K32(qb, kf1, T);
            if (m == M - 1) {                  // diagonal chunk: mask C > c
                #pragma unroll
                for (int r = 0; r < 4; ++r)
                    if (q4*4 + r > il) T[r] = -1e30f;
            }
            f16x4 pf;
            #pragma unroll
            for (int r = 0; r < 4; ++r) pf[r] = (_Float16)__expf(T[r]);
            lacc = MFMA_F16_K16(pf, ones, lacc);
            #pragma unroll
            for (int ht = 0; ht < 4; ++ht)
                o[ht] = MFMA_F16_K16(pf, va[ht], o[ht]);

            qa = qa_n; qb = qb_n;
            #pragma unroll
            for (int ht = 0; ht < 4; ++ht) va[ht] = va_n[ht];
        }
    }

    // ---- combine quarters via LDS (stride 20 floats: conflict-free b128)
    __syncthreads();
    if (qtr) {
        float* p = &smc[qtr - 1][wsub][lane][0];
        #pragma unroll
        for (int ht = 0; ht < 4; ++ht) *(f32x4*)(p + ht*4) = o[ht];
        *(f32x4*)(p + 16) = lacc;
    }
    __syncthreads();
    if (qtr == 0) {
        #pragma unroll
        for (int pq = 0; pq < 3; ++pq) {
            const float* p = &smc[pq][wsub][lane][0];
            #pragma unroll
            for (int ht = 0; ht < 4; ++ht) o[ht] += *(const f32x4*)(p + ht*4);
            lacc += *(const f32x4*)(p + 16);
        }
        float inv[4];
        #pragma unroll
        for (int r = 0; r < 4; ++r) inv[r] = 1.0f / lacc[r];
        // O C/D layout: row (c-local) = q4*4+r, col (h-local) = il (+16*ht)
        #pragma unroll
        for (int ht = 0; ht < 4; ++ht)
            #pragma unroll
            for (int r = 0; r < 4; ++r) {
                long row = c0 + wsub*16 + q4*4 + r;
                Z[row * DE + a*64 + ht*16 + il] = (__bf16)(o[ht][r] * inv[r]);
            }
    }
}

// bf16 Z for the out-projection: attn writes __bf16 directly (above).

// ---------------------------------------------------------------------------
extern "C" void kernel_launch(void* const* d_in, const int* in_sizes, int n_in,
                              void* d_out, int out_size, void* d_ws, size_t ws_size,
                              hipStream_t stream)
{
    const float* x  = (const float*)d_in[0];
    const float* Wq = (const float*)d_in[1];
    const float* Wk = (const float*)d_in[2];
    const float* Wv = (const float*)d_in[3];
    const float* Wo = (const float*)d_in[4];
    float* out = (float*)d_out;

    const long M1 = 1024 * 1024;
    __bf16* wsb  = (__bf16*)d_ws;              // 14M 2B elems = 28 MB
    __bf16* xb   = wsb;                        // [c][e]        2M bf16
    __bf16* wqb  = wsb + 2*M1;                 // [a*64+h][e]   1M bf16
    __bf16* wkb  = wsb + 3*M1;                 // (pre-scaled 0.125)
    __bf16* wvb  = wsb + 4*M1;
    __bf16* wotb = wsb + 5*M1;                 // [e][a*64+h]   1M bf16
    __half* qkh  = (__half*)(wsb + 6*M1);      // q then k: [a][c][h] f16, 4M
    __half* vth  = (__half*)(wsb + 10*M1);     // [a][h][c] f16  2M
    __bf16* zb   = wsb + 12*M1;                // [c][a*64+h] bf16 2M
    (void)wkb; (void)wvb;

    conv_all<<<3072, 256, 0, stream>>>(x, Wq, Wk, Wv, Wo,
                                       xb, wqb, wkb, wvb, wotb);

    // fused QKV: B = [wq|wk|wv] (3072 x 1024) -> q/k f16 + v^T f16
    gemm128<0><<<dim3(48, 16), 256, 0, stream>>>(xb, wqb, qkh, vth, nullptr);

    attn_mfma<<<dim3(NH, 32), 1024, 0, stream>>>(qkh, qkh + 2*M1, vth, zb);

    // output projection: out = Z · WoT^T (f32 out)
    gemm128<1><<<dim3(16, 16), 256, 0, stream>>>(zb, wotb, nullptr, nullptr, out);
}